// Round 3
// baseline (48.311 us; speedup 1.0000x reference)
//
#include <hip/hip_runtime.h>
#include <math.h>

// Problem constants (from reference)
constexpr int Wd = 320, Ht = 240;
constexpr int NB = 16, NV = 48, NBATCH = 16;
constexpr float BG = 100.0f, CMIN = 0.01f;

constexpr int QPI = Wd * Ht / 4;   // 19200 quad-pixels (float4 units) per image
constexpr int BPB = QPI / 256;     // 75 blocks per batch image

typedef float f32x4 __attribute__((ext_vector_type(4)));  // native vector: nontemporal-store OK

__global__ __launch_bounds__(256) void render_kernel(
    const float* __restrict__ tmats,   // [B][NB][4][4] f32
    const float* __restrict__ verts,   // [NV][4] f32 (w component == 1)
    const float* __restrict__ rads,    // [NV] f32
    const int*   __restrict__ bidx,    // [NV] i32
    float* __restrict__ out)           // part_maps [B][NV][H][W] then depth_maps [B][H][W]
{
    __shared__ float sX[NV], sY[NV], sZ[NV], sR2[NV];

    const int tid = threadIdx.x;
    const int b   = blockIdx.x / BPB;

    // --- skinning: 48 tiny matvecs, sequential-rounded to match numpy einsum ---
    if (tid < NV) {
        const int v  = tid;
        const int bi = bidx[v];
        const float* T = tmats + (size_t)(b * NB + bi) * 16;
        const float vx = verts[4 * v + 0];
        const float vy = verts[4 * v + 1];
        const float vz = verts[4 * v + 2];
        const float vw = verts[4 * v + 3];

        float a0 = __fmul_rn(T[0], vx);
        a0 = __fadd_rn(a0, __fmul_rn(T[1], vy));
        a0 = __fadd_rn(a0, __fmul_rn(T[2], vz));
        a0 = __fadd_rn(a0, __fmul_rn(T[3], vw));
        sX[v] = a0;

        float a1 = __fmul_rn(T[4], vx);
        a1 = __fadd_rn(a1, __fmul_rn(T[5], vy));
        a1 = __fadd_rn(a1, __fmul_rn(T[6], vz));
        a1 = __fadd_rn(a1, __fmul_rn(T[7], vw));
        sY[v] = a1;

        float a2 = __fmul_rn(T[8], vx);
        a2 = __fadd_rn(a2, __fmul_rn(T[9], vy));
        a2 = __fadd_rn(a2, __fmul_rn(T[10], vz));
        a2 = __fadd_rn(a2, __fmul_rn(T[11], vw));
        sZ[v] = a2;

        const float r = rads[v];
        sR2[v] = __fmul_rn(r, r);
    }
    __syncthreads();

    // --- per-thread: 4 consecutive w pixels of one row of one batch image ---
    const int q  = (blockIdx.x % BPB) * 256 + tid;  // 0..19199
    const int h  = q / (Wd / 4);
    const int w0 = (q % (Wd / 4)) * 4;

    // exact grid coords: (w-160)*0.9375 and (h-120)*1.25 are exactly representable
    const float yg = __fmul_rn((float)(h - Ht / 2), 1.25f);
    float xg[4], dmin[4];
#pragma unroll
    for (int k = 0; k < 4; ++k) {
        xg[k]   = __fmul_rn((float)(w0 + k - Wd / 2), 0.9375f);
        dmin[k] = INFINITY;
    }

    const size_t pix  = (size_t)h * Wd + w0;
    float* part = out + (size_t)b * NV * Ht * Wd + pix;

    for (int v = 0; v < NV; ++v) {
        const float X = sX[v], Y = sY[v], Z = sZ[v], R2 = sR2[v];
        const float dy  = __fsub_rn(yg, Y);
        const float dy2 = __fmul_rn(dy, dy);

        float o[4];
#pragma unroll
        for (int k = 0; k < 4; ++k) {
            const float dx  = __fsub_rn(xg[k], X);
            const float dx2 = __fmul_rn(dx, dx);
            // numpy order: (r2 - dx2) - dy2, each individually rounded, no FMA
            const float sq  = __fsub_rn(__fsub_rn(R2, dx2), dy2);
            const float s   = __fsqrt_rn(fmaxf(sq, CMIN));  // IEEE sqrt = np.sqrt
            const float val = (sq > CMIN) ? __fsub_rn(Z, s) : BG;
            o[k]    = val;
            dmin[k] = fminf(dmin[k], val);
        }
        // streaming store: part_maps are written once, never re-read — bypass L2 allocate
        f32x4 ov = {o[0], o[1], o[2], o[3]};
        __builtin_nontemporal_store(ov,
            reinterpret_cast<f32x4*>(part + (size_t)v * (Ht * Wd)));
    }

    float* depth = out + (size_t)NBATCH * NV * Ht * Wd + (size_t)b * Ht * Wd + pix;
    f32x4 dv = {dmin[0], dmin[1], dmin[2], dmin[3]};
    __builtin_nontemporal_store(dv, reinterpret_cast<f32x4*>(depth));
}

extern "C" void kernel_launch(void* const* d_in, const int* in_sizes, int n_in,
                              void* d_out, int out_size, void* d_ws, size_t ws_size,
                              hipStream_t stream) {
    const float* tmats = (const float*)d_in[0];  // (16,16,4,4)
    const float* verts = (const float*)d_in[1];  // (48,4)
    const float* rads  = (const float*)d_in[2];  // (48,)
    const int*   bidx  = (const int*)d_in[3];    // (48,)
    float* out = (float*)d_out;

    dim3 grid(NBATCH * BPB);  // 1200 blocks
    dim3 block(256);
    render_kernel<<<grid, block, 0, stream>>>(tmats, verts, rads, bidx, out);
}

// Round 4
// 46.941 us; speedup vs baseline: 1.0292x; 1.0292x over previous
//
#include <hip/hip_runtime.h>
#include <math.h>

// Problem constants (from reference)
constexpr int Wd = 320, Ht = 240;
constexpr int NB = 16, NV = 48, NBATCH = 16;
constexpr float BG = 100.0f, CMIN = 0.01f;

constexpr int PPT = 8;                     // pixels per thread (two float4 stores)
constexpr int UPI = Wd * Ht / PPT;         // 9600 work units per image
constexpr int BPB = UPI / 256;             // 37.5 -> use 2 images per 75 blocks? No:
// 9600/256 = 37.5 not integer. Use 128-thread blocks: 9600/128 = 75 blocks per image.
constexpr int TPB = 128;
constexpr int BPB2 = UPI / TPB;            // 75 blocks per batch image

typedef float f32x4 __attribute__((ext_vector_type(4)));

__global__ __launch_bounds__(TPB) void render_kernel(
    const float* __restrict__ tmats,   // [B][NB][4][4] f32
    const float* __restrict__ verts,   // [NV][4] f32 (w component == 1)
    const float* __restrict__ rads,    // [NV] f32
    const int*   __restrict__ bidx,    // [NV] i32
    float* __restrict__ out)           // part_maps [B][NV][H][W] then depth_maps [B][H][W]
{
    __shared__ float sX[NV], sY[NV], sZ[NV], sR2[NV];

    const int tid = threadIdx.x;
    const int b   = blockIdx.x / BPB2;

    // --- skinning: 48 tiny matvecs, sequential-rounded to match numpy einsum ---
    if (tid < NV) {
        const int v  = tid;
        const int bi = bidx[v];
        const float* T = tmats + (size_t)(b * NB + bi) * 16;
        const float vx = verts[4 * v + 0];
        const float vy = verts[4 * v + 1];
        const float vz = verts[4 * v + 2];
        const float vw = verts[4 * v + 3];

        float a0 = __fmul_rn(T[0], vx);
        a0 = __fadd_rn(a0, __fmul_rn(T[1], vy));
        a0 = __fadd_rn(a0, __fmul_rn(T[2], vz));
        a0 = __fadd_rn(a0, __fmul_rn(T[3], vw));
        sX[v] = a0;

        float a1 = __fmul_rn(T[4], vx);
        a1 = __fadd_rn(a1, __fmul_rn(T[5], vy));
        a1 = __fadd_rn(a1, __fmul_rn(T[6], vz));
        a1 = __fadd_rn(a1, __fmul_rn(T[7], vw));
        sY[v] = a1;

        float a2 = __fmul_rn(T[8], vx);
        a2 = __fadd_rn(a2, __fmul_rn(T[9], vy));
        a2 = __fadd_rn(a2, __fmul_rn(T[10], vz));
        a2 = __fadd_rn(a2, __fmul_rn(T[11], vw));
        sZ[v] = a2;

        const float r = rads[v];
        sR2[v] = __fmul_rn(r, r);
    }
    __syncthreads();

    // --- per-thread: 8 consecutive w pixels of one row of one batch image ---
    const int q  = (blockIdx.x % BPB2) * TPB + tid;  // 0..9599
    const int h  = q / (Wd / PPT);
    const int w0 = (q % (Wd / PPT)) * PPT;

    // exact grid coords: (w-160)*0.9375 and (h-120)*1.25 are exactly representable
    const float yg = __fmul_rn((float)(h - Ht / 2), 1.25f);
    float xg[PPT], dmin[PPT];
#pragma unroll
    for (int k = 0; k < PPT; ++k) {
        xg[k]   = __fmul_rn((float)(w0 + k - Wd / 2), 0.9375f);
        dmin[k] = INFINITY;
    }

    const size_t pix  = (size_t)h * Wd + w0;
    float* part = out + (size_t)b * NV * Ht * Wd + pix;

    for (int v = 0; v < NV; ++v) {
        const float X = sX[v], Y = sY[v], Z = sZ[v], R2 = sR2[v];
        const float dy  = __fsub_rn(yg, Y);
        const float dy2 = __fmul_rn(dy, dy);

        float o[PPT];
#pragma unroll
        for (int k = 0; k < PPT; ++k) {
            const float dx  = __fsub_rn(xg[k], X);
            const float dx2 = __fmul_rn(dx, dx);
            // numpy order: (r2 - dx2) - dy2, each individually rounded, no FMA
            const float sq  = __fsub_rn(__fsub_rn(R2, dx2), dy2);
            const float s   = __fsqrt_rn(fmaxf(sq, CMIN));  // IEEE sqrt = np.sqrt
            const float val = (sq > CMIN) ? __fsub_rn(Z, s) : BG;
            o[k]    = val;
            dmin[k] = fminf(dmin[k], val);
        }
        float* p = part + (size_t)v * (Ht * Wd);
        *reinterpret_cast<f32x4*>(p)     = f32x4{o[0], o[1], o[2], o[3]};
        *reinterpret_cast<f32x4*>(p + 4) = f32x4{o[4], o[5], o[6], o[7]};
    }

    float* depth = out + (size_t)NBATCH * NV * Ht * Wd + (size_t)b * Ht * Wd + pix;
    *reinterpret_cast<f32x4*>(depth)     = f32x4{dmin[0], dmin[1], dmin[2], dmin[3]};
    *reinterpret_cast<f32x4*>(depth + 4) = f32x4{dmin[4], dmin[5], dmin[6], dmin[7]};
}

extern "C" void kernel_launch(void* const* d_in, const int* in_sizes, int n_in,
                              void* d_out, int out_size, void* d_ws, size_t ws_size,
                              hipStream_t stream) {
    const float* tmats = (const float*)d_in[0];  // (16,16,4,4)
    const float* verts = (const float*)d_in[1];  // (48,4)
    const float* rads  = (const float*)d_in[2];  // (48,)
    const int*   bidx  = (const int*)d_in[3];    // (48,)
    float* out = (float*)d_out;

    dim3 grid(NBATCH * BPB2);  // 1200 blocks of 128 threads
    dim3 block(TPB);
    render_kernel<<<grid, block, 0, stream>>>(tmats, verts, rads, bidx, out);
}

// Round 5
// 41.882 us; speedup vs baseline: 1.1535x; 1.1208x over previous
//
#include <hip/hip_runtime.h>
#include <math.h>

// Problem constants (from reference)
constexpr int Wd = 320, Ht = 240;
constexpr int NB = 16, NV = 48, NBATCH = 16;
constexpr float BG = 100.0f, CMIN = 0.01f;

constexpr int PPT = 2;                    // pixels per thread (one float2 store per plane)
constexpr int TPB = 256;
constexpr int UPI = Wd * Ht / PPT;        // 38400 work units per image
constexpr int BPB = UPI / TPB;            // 150 blocks per batch image

typedef float f32x2 __attribute__((ext_vector_type(2)));

__global__ __launch_bounds__(TPB) void render_kernel(
    const float* __restrict__ tmats,   // [B][NB][4][4] f32
    const float* __restrict__ verts,   // [NV][4] f32 (w component == 1)
    const float* __restrict__ rads,    // [NV] f32
    const int*   __restrict__ bidx,    // [NV] i32
    float* __restrict__ out)           // part_maps [B][NV][H][W] then depth_maps [B][H][W]
{
    __shared__ float sX[NV], sY[NV], sZ[NV], sR2[NV];

    const int tid = threadIdx.x;
    const int b   = blockIdx.x / BPB;

    // --- skinning: 48 tiny matvecs, sequential-rounded to match numpy einsum ---
    if (tid < NV) {
        const int v  = tid;
        const int bi = bidx[v];
        const float* T = tmats + (size_t)(b * NB + bi) * 16;
        const float vx = verts[4 * v + 0];
        const float vy = verts[4 * v + 1];
        const float vz = verts[4 * v + 2];
        const float vw = verts[4 * v + 3];

        float a0 = __fmul_rn(T[0], vx);
        a0 = __fadd_rn(a0, __fmul_rn(T[1], vy));
        a0 = __fadd_rn(a0, __fmul_rn(T[2], vz));
        a0 = __fadd_rn(a0, __fmul_rn(T[3], vw));
        sX[v] = a0;

        float a1 = __fmul_rn(T[4], vx);
        a1 = __fadd_rn(a1, __fmul_rn(T[5], vy));
        a1 = __fadd_rn(a1, __fmul_rn(T[6], vz));
        a1 = __fadd_rn(a1, __fmul_rn(T[7], vw));
        sY[v] = a1;

        float a2 = __fmul_rn(T[8], vx);
        a2 = __fadd_rn(a2, __fmul_rn(T[9], vy));
        a2 = __fadd_rn(a2, __fmul_rn(T[10], vz));
        a2 = __fadd_rn(a2, __fmul_rn(T[11], vw));
        sZ[v] = a2;

        const float r = rads[v];
        sR2[v] = __fmul_rn(r, r);
    }
    __syncthreads();

    // --- per-thread: 2 consecutive w pixels of one row of one batch image ---
    const int q  = (blockIdx.x % BPB) * TPB + tid;  // 0..38399
    const int h  = q / (Wd / PPT);
    const int w0 = (q % (Wd / PPT)) * PPT;

    // exact grid coords: (w-160)*0.9375 and (h-120)*1.25 are exactly representable
    const float yg = __fmul_rn((float)(h - Ht / 2), 1.25f);
    float xg[PPT], dmin[PPT];
#pragma unroll
    for (int k = 0; k < PPT; ++k) {
        xg[k]   = __fmul_rn((float)(w0 + k - Wd / 2), 0.9375f);
        dmin[k] = INFINITY;
    }

    const size_t pix  = (size_t)h * Wd + w0;
    float* part = out + (size_t)b * NV * Ht * Wd + pix;

    for (int v = 0; v < NV; ++v) {
        const float X = sX[v], Y = sY[v], Z = sZ[v], R2 = sR2[v];
        const float dy  = __fsub_rn(yg, Y);
        const float dy2 = __fmul_rn(dy, dy);

        float o[PPT];
#pragma unroll
        for (int k = 0; k < PPT; ++k) {
            const float dx  = __fsub_rn(xg[k], X);
            const float dx2 = __fmul_rn(dx, dx);
            // numpy order: (r2 - dx2) - dy2, each individually rounded, no FMA
            const float sq  = __fsub_rn(__fsub_rn(R2, dx2), dy2);
            const float s   = __fsqrt_rn(fmaxf(sq, CMIN));  // IEEE sqrt = np.sqrt
            const float val = (sq > CMIN) ? __fsub_rn(Z, s) : BG;
            o[k]    = val;
            dmin[k] = fminf(dmin[k], val);
        }
        *reinterpret_cast<f32x2*>(part + (size_t)v * (Ht * Wd)) = f32x2{o[0], o[1]};
    }

    float* depth = out + (size_t)NBATCH * NV * Ht * Wd + (size_t)b * Ht * Wd + pix;
    *reinterpret_cast<f32x2*>(depth) = f32x2{dmin[0], dmin[1]};
}

extern "C" void kernel_launch(void* const* d_in, const int* in_sizes, int n_in,
                              void* d_out, int out_size, void* d_ws, size_t ws_size,
                              hipStream_t stream) {
    const float* tmats = (const float*)d_in[0];  // (16,16,4,4)
    const float* verts = (const float*)d_in[1];  // (48,4)
    const float* rads  = (const float*)d_in[2];  // (48,)
    const int*   bidx  = (const int*)d_in[3];    // (48,)
    float* out = (float*)d_out;

    dim3 grid(NBATCH * BPB);  // 2400 blocks of 256 threads
    dim3 block(TPB);
    render_kernel<<<grid, block, 0, stream>>>(tmats, verts, rads, bidx, out);
}

// Round 6
// 40.973 us; speedup vs baseline: 1.1791x; 1.0222x over previous
//
#include <hip/hip_runtime.h>
#include <math.h>

// Problem constants (from reference)
constexpr int Wd = 320, Ht = 240;
constexpr int NB = 16, NV = 48, NBATCH = 16;
constexpr float BG = 100.0f, CMIN = 0.01f;

constexpr int QPI = Wd * Ht / 4;   // 19200 quad-pixels (float4 units) per image
constexpr int BPB = QPI / 256;     // 75 blocks per batch image

typedef float f32x4 __attribute__((ext_vector_type(4)));

// Final config (bracketed R1/R3/R4/R5): 4 px/thread, 256 threads, 1200 blocks,
// plain L2-allocating dwordx4 stores. nt-stores regress (-17%); 8px/thread
// regresses (-14%); 2px/thread neutral-worse (-2%).
__global__ __launch_bounds__(256) void render_kernel(
    const float* __restrict__ tmats,   // [B][NB][4][4] f32
    const float* __restrict__ verts,   // [NV][4] f32 (w component == 1)
    const float* __restrict__ rads,    // [NV] f32
    const int*   __restrict__ bidx,    // [NV] i32
    float* __restrict__ out)           // part_maps [B][NV][H][W] then depth_maps [B][H][W]
{
    __shared__ float sX[NV], sY[NV], sZ[NV], sR2[NV];

    const int tid = threadIdx.x;
    const int b   = blockIdx.x / BPB;

    // --- skinning: 48 tiny matvecs, sequential-rounded to match numpy einsum ---
    if (tid < NV) {
        const int v  = tid;
        const int bi = bidx[v];
        const float* T = tmats + (size_t)(b * NB + bi) * 16;
        const float vx = verts[4 * v + 0];
        const float vy = verts[4 * v + 1];
        const float vz = verts[4 * v + 2];
        const float vw = verts[4 * v + 3];

        float a0 = __fmul_rn(T[0], vx);
        a0 = __fadd_rn(a0, __fmul_rn(T[1], vy));
        a0 = __fadd_rn(a0, __fmul_rn(T[2], vz));
        a0 = __fadd_rn(a0, __fmul_rn(T[3], vw));
        sX[v] = a0;

        float a1 = __fmul_rn(T[4], vx);
        a1 = __fadd_rn(a1, __fmul_rn(T[5], vy));
        a1 = __fadd_rn(a1, __fmul_rn(T[6], vz));
        a1 = __fadd_rn(a1, __fmul_rn(T[7], vw));
        sY[v] = a1;

        float a2 = __fmul_rn(T[8], vx);
        a2 = __fadd_rn(a2, __fmul_rn(T[9], vy));
        a2 = __fadd_rn(a2, __fmul_rn(T[10], vz));
        a2 = __fadd_rn(a2, __fmul_rn(T[11], vw));
        sZ[v] = a2;

        const float r = rads[v];
        sR2[v] = __fmul_rn(r, r);
    }
    __syncthreads();

    // --- per-thread: 4 consecutive w pixels of one row of one batch image ---
    const int q  = (blockIdx.x % BPB) * 256 + tid;  // 0..19199
    const int h  = q / (Wd / 4);
    const int w0 = (q % (Wd / 4)) * 4;

    // exact grid coords: (w-160)*0.9375 and (h-120)*1.25 are exactly representable
    const float yg = __fmul_rn((float)(h - Ht / 2), 1.25f);
    float xg[4], dmin[4];
#pragma unroll
    for (int k = 0; k < 4; ++k) {
        xg[k]   = __fmul_rn((float)(w0 + k - Wd / 2), 0.9375f);
        dmin[k] = INFINITY;
    }

    const size_t pix  = (size_t)h * Wd + w0;
    float* part = out + (size_t)b * NV * Ht * Wd + pix;

    for (int v = 0; v < NV; ++v) {
        const float X = sX[v], Y = sY[v], Z = sZ[v], R2 = sR2[v];
        const float dy  = __fsub_rn(yg, Y);
        const float dy2 = __fmul_rn(dy, dy);

        float o[4];
#pragma unroll
        for (int k = 0; k < 4; ++k) {
            const float dx  = __fsub_rn(xg[k], X);
            const float dx2 = __fmul_rn(dx, dx);
            // numpy order: (r2 - dx2) - dy2, each individually rounded, no FMA
            const float sq  = __fsub_rn(__fsub_rn(R2, dx2), dy2);
            const float s   = __fsqrt_rn(fmaxf(sq, CMIN));  // IEEE sqrt = np.sqrt
            const float val = (sq > CMIN) ? __fsub_rn(Z, s) : BG;
            o[k]    = val;
            dmin[k] = fminf(dmin[k], val);
        }
        *reinterpret_cast<f32x4*>(part + (size_t)v * (Ht * Wd)) =
            f32x4{o[0], o[1], o[2], o[3]};
    }

    float* depth = out + (size_t)NBATCH * NV * Ht * Wd + (size_t)b * Ht * Wd + pix;
    *reinterpret_cast<f32x4*>(depth) = f32x4{dmin[0], dmin[1], dmin[2], dmin[3]};
}

extern "C" void kernel_launch(void* const* d_in, const int* in_sizes, int n_in,
                              void* d_out, int out_size, void* d_ws, size_t ws_size,
                              hipStream_t stream) {
    const float* tmats = (const float*)d_in[0];  // (16,16,4,4)
    const float* verts = (const float*)d_in[1];  // (48,4)
    const float* rads  = (const float*)d_in[2];  // (48,)
    const int*   bidx  = (const int*)d_in[3];    // (48,)
    float* out = (float*)d_out;

    dim3 grid(NBATCH * BPB);  // 1200 blocks
    dim3 block(256);
    render_kernel<<<grid, block, 0, stream>>>(tmats, verts, rads, bidx, out);
}